// Round 22
// baseline (145.135 us; speedup 1.0000x reference)
//
#include <hip/hip_runtime.h>
#include <hip/hip_bf16.h>
#include <math.h>

#define B_    4
#define C_    128
#define H_    96
#define W_    96
#define HW_   9216          // H*W
#define NPIX  36864         // B*HW
#define BHWC  4718592       // B*HW*C
#define BATCH_STRIDE 1179648 // HW*C

typedef __attribute__((ext_vector_type(8))) short bfrag8;
typedef __attribute__((ext_vector_type(4))) float f32x4;

static __device__ __forceinline__ short f2bf(float f) {
  __hip_bfloat16 h = __float2bfloat16(f);
  short s;
  __builtin_memcpy(&s, &h, 2);
  return s;
}
static __device__ __forceinline__ float bf2f(short s) {
  unsigned u = ((unsigned)(unsigned short)s) << 16;
  float f;
  __builtin_memcpy(&f, &u, 4);
  return f;
}
// pack two f32 -> two bf16 (RNE) in one instruction
static __device__ __forceinline__ unsigned cvtpk(float lo, float hi) {
  unsigned r;
  asm("v_cvt_pk_bf16_f32 %0, %1, %2" : "=v"(r) : "v"(lo), "v"(hi));
  return r;
}

// ---------------- weight transposes (+ zero stats accumulators) ------------
__global__ void k_transpose_w(const float* __restrict__ de_w,
                              const float* __restrict__ off_w,
                              const float* __restrict__ pw_w,
                              short* __restrict__ wtb, short* __restrict__ wob,
                              short* __restrict__ pwb, float* __restrict__ ist) {
  int i = blockIdx.x * 256 + threadIdx.x;
  if (i < 147456) {
    int j  = i & 7;
    int l  = (i >> 3) & 63;
    int kk = (i >> 9) & 3;
    int mt = (i >> 11) & 7;
    int k  = i >> 14;
    int oc = mt * 16 + (l & 15);
    int c  = kk * 32 + ((l >> 4) << 3) + j;
    wtb[i] = f2bf(de_w[(oc * 128 + c) * 9 + k]);
  }
  if (i < 36864) {
    int j  = i & 7;
    int l  = (i >> 3) & 63;
    int kk = (i >> 9) & 3;
    int mt = (i >> 11) & 1;
    int k  = i >> 12;
    int oc = mt * 16 + (l & 15);
    int c  = kk * 32 + ((l >> 4) << 3) + j;
    wob[i] = (oc < 18) ? f2bf(off_w[(oc * 128 + c) * 9 + k]) : (short)0;
  }
  if (i < 16384) {
    int j  = i & 7;
    int l  = (i >> 3) & 63;
    int kk = (i >> 9) & 3;
    int mt = i >> 11;
    int oc = mt * 16 + (l & 15);
    int c  = kk * 32 + ((l >> 4) << 3) + j;
    pwb[i] = f2bf(pw_w[oc * 128 + c]);
  }
  if (i < 1032) ist[i] = 0.f;   // zero ist[1024] + gst[8]
}

// ------ fused depthwise+pointwise MFMA + IN-stats, 32-pix blocks -----------
// block = 32 pix x 128 oc, 4 waves; grid NPIX/32 = 1152 (occupancy fix).
// Stage: thread (pixloc=tid&31, cq=tid>>5) computes dw 3x3 for 16 channels
// (2 c8-groups). MFMA: wave wv = pixblk (wv&1) x mt-half (wv>>1), acc[4].
// Stats: ps[wv][64] per-wave oc-half partials; final: sum both pixblk waves.
__global__ __launch_bounds__(256) void k_pw(
    const float* __restrict__ x, const float* __restrict__ dw_w,
    const float* __restrict__ dw_b, const short* __restrict__ pwb,
    const float* __restrict__ pw_b, short* __restrict__ sbf,
    float* __restrict__ ist) {
  __shared__ short lb[2][4][64][8];   // [pb][kk][lane][j], 8 KB
  __shared__ float ps[4][64], pq2[4][64];  // 2 KB stats partials
  int tid = threadIdx.x;
  int pixbase = blockIdx.x * 32;
  int b = pixbase / HW_;
  int hw0 = pixbase % HW_;

  int pixloc = tid & 31, cq = tid >> 5;   // cq 0..7
  {
    int hw = hw0 + pixloc;
    int y = hw / 96, xx = hw % 96;
    const float* xb = x + (size_t)b * 128 * HW_;
    int toff[9];
    float tmask[9];
    #pragma unroll
    for (int dy = 0; dy < 3; ++dy) {
      #pragma unroll
      for (int dx = 0; dx < 3; ++dx) {
        int sy = y + dy - 1, sx = xx + dx - 1;
        bool vld = ((unsigned)sy < 96u) && ((unsigned)sx < 96u);
        int syc = min(max(sy, 0), 95), sxc = min(max(sx, 0), 95);
        toff[dy * 3 + dx] = syc * 96 + sxc;
        tmask[dy * 3 + dx] = vld ? 1.f : 0.f;
      }
    }
    #pragma unroll
    for (int it = 0; it < 2; ++it) {
      int c8 = cq * 2 + it;
      int c0 = c8 * 8;
      float v[8];
      #pragma unroll
      for (int j = 0; j < 8; ++j) {
        int c = c0 + j;
        const float* xp = xb + (size_t)c * HW_;
        const float* wp = dw_w + c * 9;
        float a = dw_b[c];
        #pragma unroll
        for (int t9 = 0; t9 < 9; ++t9)
          a = fmaf(xp[toff[t9]] * tmask[t9], wp[t9], a);
        v[j] = a;
      }
      unsigned o0 = cvtpk(v[0], v[1]), o1 = cvtpk(v[2], v[3]);
      unsigned o2 = cvtpk(v[4], v[5]), o3 = cvtpk(v[6], v[7]);
      *(uint4*)&lb[pixloc >> 4][c8 >> 2][(c8 & 3) * 16 + (pixloc & 15)][0] =
          make_uint4(o0, o1, o2, o3);
    }
  }
  __syncthreads();

  int lane = tid & 63, wv = tid >> 6;
  int lp = lane & 15, g = lane >> 4;
  int pb = wv & 1;           // pixblk
  int mt0 = (wv >> 1) * 4;   // mt half: 4 consecutive 16-oc tiles
  const bfrag8* wp8 = (const bfrag8*)pwb;

  f32x4 acc[4];
  #pragma unroll
  for (int m = 0; m < 4; ++m) acc[m] = (f32x4){0.f, 0.f, 0.f, 0.f};

  #pragma unroll
  for (int kk = 0; kk < 4; ++kk) {
    bfrag8 Bf = *(const bfrag8*)&lb[pb][kk][lane][0];
    #pragma unroll
    for (int m = 0; m < 4; ++m) {
      bfrag8 af = wp8[((size_t)((mt0 + m) * 4 + kk)) * 64 + lane];
      acc[m] = __builtin_amdgcn_mfma_f32_16x16x32_bf16(af, Bf, acc[m], 0, 0, 0);
    }
  }

  int pix = pixbase + pb * 16 + lp;
  #pragma unroll
  for (int m = 0; m < 4; ++m) {
    int oc = (mt0 + m) * 16 + g * 4;
    float4 bias = *(const float4*)(pw_b + oc);
    f32x4 a = acc[m];
    float4 v = make_float4(a[0] + bias.x, a[1] + bias.y, a[2] + bias.z, a[3] + bias.w);
    *(uint2*)(sbf + (size_t)pix * 128 + oc) = make_uint2(cvtpk(v.x, v.y), cvtpk(v.z, v.w));
    float t0 = v.x, t1 = v.y, t2 = v.z, t3 = v.w;
    float u0 = v.x * v.x, u1 = v.y * v.y, u2 = v.z * v.z, u3 = v.w * v.w;
    #pragma unroll
    for (int mask = 1; mask <= 8; mask <<= 1) {
      t0 += __shfl_xor(t0, mask); t1 += __shfl_xor(t1, mask);
      t2 += __shfl_xor(t2, mask); t3 += __shfl_xor(t3, mask);
      u0 += __shfl_xor(u0, mask); u1 += __shfl_xor(u1, mask);
      u2 += __shfl_xor(u2, mask); u3 += __shfl_xor(u3, mask);
    }
    if (lp == 0) {
      int loc = m * 16 + g * 4;   // oc local to this wave's 64-oc half
      ps[wv][loc + 0] = t0; ps[wv][loc + 1] = t1; ps[wv][loc + 2] = t2; ps[wv][loc + 3] = t3;
      pq2[wv][loc + 0] = u0; pq2[wv][loc + 1] = u1; pq2[wv][loc + 2] = u2; pq2[wv][loc + 3] = u3;
    }
  }
  __syncthreads();
  if (tid < 128) {
    int h = tid >> 6, loc = tid & 63;
    float su = ps[h * 2 + 0][loc] + ps[h * 2 + 1][loc];
    float sq = pq2[h * 2 + 0][loc] + pq2[h * 2 + 1][loc];
    atomicAdd(&ist[(size_t)(b * 128 + tid) * 2],     su);
    atomicAdd(&ist[(size_t)(b * 128 + tid) * 2 + 1], sq);
  }
}

// ---------------- normalize sbf(bf16) -> bf16 pixel-major nsamp ------------
__global__ __launch_bounds__(256) void k_norm(
    const short* __restrict__ sbf, const float* __restrict__ ist,
    short* __restrict__ nsamp) {
  int t = blockIdx.x * 256 + threadIdx.x;   // t < NPIX*16
  int pix = t >> 4; int c0 = (t & 15) * 8;
  int b = pix / HW_;
  bfrag8 sv = *(const bfrag8*)(sbf + (size_t)pix * 128 + c0);
  bfrag8 o;
  #pragma unroll
  for (int j = 0; j < 8; ++j) {
    size_t ci = (size_t)(b * 128 + c0 + j) * 2;
    float mean = ist[ci] * (1.f / 9216.f);
    float var  = ist[ci + 1] * (1.f / 9216.f) - mean * mean;
    float rs = rsqrtf(var + 1e-5f);
    o[j] = f2bf(fmaxf((bf2f(sv[j]) - mean) * rs, 0.f));
  }
  *(bfrag8*)(nsamp + (size_t)pix * 128 + c0) = o;
}

// ---------------- offset conv as MFMA GEMM with shifted fragments ----------
__global__ __launch_bounds__(256) void k_offgemm(
    const short* __restrict__ nsamp, const short* __restrict__ wob,
    const float* __restrict__ off_b, float* __restrict__ off) {
  int tid = threadIdx.x;
  int lane = tid & 63, wv = tid >> 6;
  int p0 = blockIdx.x * 128 + wv * 32;
  int lp = lane & 15, g = lane >> 4;
  const bfrag8* np = (const bfrag8*)nsamp;
  const bfrag8* wp = (const bfrag8*)wob;

  f32x4 acc[2][2];
  #pragma unroll
  for (int m = 0; m < 2; ++m)
    #pragma unroll
    for (int n = 0; n < 2; ++n) acc[m][n] = (f32x4){0.f, 0.f, 0.f, 0.f};

  int pn0 = p0 + lp, pn1 = p0 + 16 + lp;
  int x0_ = pn0 % 96, y0_ = (pn0 % HW_) / 96;
  int x1_ = pn1 % 96, y1_ = (pn1 % HW_) / 96;
  const bfrag8 zf = {0, 0, 0, 0, 0, 0, 0, 0};

  for (int k = 0; k < 9; ++k) {
    int dy = k / 3 - 1, dx = k % 3 - 1;
    int sh = dy * 96 + dx;
    bool v0 = ((unsigned)(x0_ + dx) < 96u) && ((unsigned)(y0_ + dy) < 96u);
    bool v1 = ((unsigned)(x1_ + dx) < 96u) && ((unsigned)(y1_ + dy) < 96u);
    int q0 = min(max(pn0 + sh, 0), NPIX - 1);
    int q1 = min(max(pn1 + sh, 0), NPIX - 1);
    size_t a0 = (size_t)q0 * 16 + g;
    size_t a1 = (size_t)q1 * 16 + g;
    #pragma unroll
    for (int kk = 0; kk < 4; ++kk) {
      bfrag8 B0 = np[a0 + kk * 4]; B0 = v0 ? B0 : zf;
      bfrag8 B1 = np[a1 + kk * 4]; B1 = v1 ? B1 : zf;
      bfrag8 A0 = wp[((size_t)(k * 2 + 0) * 4 + kk) * 64 + lane];
      bfrag8 A1 = wp[((size_t)(k * 2 + 1) * 4 + kk) * 64 + lane];
      acc[0][0] = __builtin_amdgcn_mfma_f32_16x16x32_bf16(A0, B0, acc[0][0], 0, 0, 0);
      acc[0][1] = __builtin_amdgcn_mfma_f32_16x16x32_bf16(A0, B1, acc[0][1], 0, 0, 0);
      acc[1][0] = __builtin_amdgcn_mfma_f32_16x16x32_bf16(A1, B0, acc[1][0], 0, 0, 0);
      acc[1][1] = __builtin_amdgcn_mfma_f32_16x16x32_bf16(A1, B1, acc[1][1], 0, 0, 0);
    }
  }

  #pragma unroll
  for (int mt = 0; mt < 2; ++mt) {
    #pragma unroll
    for (int r = 0; r < 4; ++r) {
      int oc = mt * 16 + g * 4 + r;
      if (oc < 18) {
        float bb = off_b[oc];
        off[(size_t)oc * NPIX + p0 + lp]      = acc[mt][0][r] + bb;
        off[(size_t)oc * NPIX + p0 + 16 + lp] = acc[mt][1][r] + bb;
      }
    }
  }
}

// ---------------- fused deform: 64-pix blocks, 8 waves (R21 proven) --------
__global__ __launch_bounds__(512) void k_deform_f(
    const short* __restrict__ nsamp, const float* __restrict__ off,
    const short* __restrict__ wtb, const float* __restrict__ de_b,
    short* __restrict__ d, float* __restrict__ gst) {
  __shared__ short lbuf[2][4][16][17][8];  // 34.8 KB
  __shared__ float offl[18][64];           // 4.6 KB
  __shared__ float r1[512], r2[512];
  int tid = threadIdx.x;
  int bid = blockIdx.x;
  int wg = (bid & 7) * 72 + (bid >> 3);    // bijective for 576
  int pixbase = wg * 64;

  int lane = tid & 63, wv = tid >> 6;      // wv 0..7
  int lp = lane & 15, g = lane >> 4;
  int pq = lane >> 4, ch = lane & 15;      // sampling role

  // stage offsets for this block's 64 pixels: 18 x 64 = 1152 floats
  #pragma unroll
  for (int t = 0; t < 3; ++t) {
    int i = t * 512 + tid;
    if (i < 1152)
      offl[i >> 6][i & 63] = off[(size_t)(i >> 6) * NPIX + pixbase + (i & 63)];
  }
  __syncthreads();

  // per-q pixel constants (sampling role)
  int lpixA[2], ysA[2], xsA[2], qbA[2];
  #pragma unroll
  for (int q = 0; q < 2; ++q) {
    int lpix = wv * 8 + q * 4 + pq;
    int pix = pixbase + lpix;
    int hw = pix % HW_;
    lpixA[q] = lpix;
    ysA[q] = hw / 96;
    xsA[q] = hw % 96;
    qbA[q] = (pix / HW_) * HW_;
  }

  // mfma role
  int mtg0 = (wv & 3) * 2;
  int pb0  = (wv >> 2) * 2;
  const bfrag8* wp = (const bfrag8*)wtb;

  f32x4 acc[2][2];
  #pragma unroll
  for (int m = 0; m < 2; ++m)
    #pragma unroll
    for (int n = 0; n < 2; ++n) acc[m][n] = (f32x4){0.f, 0.f, 0.f, 0.f};

  bfrag8 cs0[2][4], cs1[2][4];   // two corner-register sets

  auto ISSUE = [&](int k, bfrag8 (&cs)[2][4]) {
    #pragma unroll
    for (int q = 0; q < 2; ++q) {
      float dy = offl[2 * k][lpixA[q]];
      float dx = offl[2 * k + 1][lpixA[q]];
      float py = (float)ysA[q] + (float)(k / 3 - 1) + dy;
      float px = (float)xsA[q] + (float)(k % 3 - 1) + dx;
      int y0 = (int)floorf(py), x0 = (int)floorf(px);
      int yc0 = min(max(y0, 0), 95), yc1 = min(max(y0 + 1, 0), 95);
      int xc0 = min(max(x0, 0), 95), xc1 = min(max(x0 + 1, 0), 95);
      const short* base = nsamp + (size_t)ch * 8;
      cs[q][0] = *(const bfrag8*)(base + (size_t)(qbA[q] + yc0 * 96 + xc0) * 128);
      cs[q][1] = *(const bfrag8*)(base + (size_t)(qbA[q] + yc0 * 96 + xc1) * 128);
      cs[q][2] = *(const bfrag8*)(base + (size_t)(qbA[q] + yc1 * 96 + xc0) * 128);
      cs[q][3] = *(const bfrag8*)(base + (size_t)(qbA[q] + yc1 * 96 + xc1) * 128);
    }
  };

  auto FINISH = [&](int k, bfrag8 (&cs)[2][4], int buf) {
    #pragma unroll
    for (int q = 0; q < 2; ++q) {
      float dy = offl[2 * k][lpixA[q]];
      float dx = offl[2 * k + 1][lpixA[q]];
      float py = (float)ysA[q] + (float)(k / 3 - 1) + dy;
      float px = (float)xsA[q] + (float)(k % 3 - 1) + dx;
      float y0f = floorf(py), x0f = floorf(px);
      float ly = py - y0f, lx = px - x0f;
      int y0 = (int)y0f, x0 = (int)x0f;
      bool vy0 = (y0 >= 0) && (y0 < 96), vy1 = (y0 + 1 >= 0) && (y0 + 1 < 96);
      bool vx0 = (x0 >= 0) && (x0 < 96), vx1 = (x0 + 1 >= 0) && (x0 + 1 < 96);
      float w00 = (vy0 && vx0) ? (1.f - ly) * (1.f - lx) : 0.f;
      float w01 = (vy0 && vx1) ? (1.f - ly) * lx : 0.f;
      float w10 = (vy1 && vx0) ? ly * (1.f - lx) : 0.f;
      float w11 = (vy1 && vx1) ? ly * lx : 0.f;
      float v[8];
      #pragma unroll
      for (int j = 0; j < 8; ++j) {
        v[j] = bf2f(cs[q][0][j]) * w00 + bf2f(cs[q][1][j]) * w01
             + bf2f(cs[q][2][j]) * w10 + bf2f(cs[q][3][j]) * w11;
      }
      unsigned o0 = cvtpk(v[0], v[1]), o1 = cvtpk(v[2], v[3]);
      unsigned o2 = cvtpk(v[4], v[5]), o3 = cvtpk(v[6], v[7]);
      int lpix = lpixA[q];
      *(uint4*)&lbuf[buf][lpix >> 4][lpix & 15][ch][0] = make_uint4(o0, o1, o2, o3);
    }
  };

  ISSUE(0, cs0);
  #pragma unroll
  for (int k = 0; k < 9; ++k) {
    if (k < 8) {
      if ((k + 1) & 1) ISSUE(k + 1, cs1);
      else             ISSUE(k + 1, cs0);
    }
    if (k & 1) FINISH(k, cs1, 1);
    else       FINISH(k, cs0, 0);
    __syncthreads();
    int cur = k & 1;
    #pragma unroll
    for (int kk = 0; kk < 4; ++kk) {
      bfrag8 B0 = *(const bfrag8*)&lbuf[cur][pb0 + 0][lp][kk * 4 + g][0];
      bfrag8 B1 = *(const bfrag8*)&lbuf[cur][pb0 + 1][lp][kk * 4 + g][0];
      #pragma unroll
      for (int m = 0; m < 2; ++m) {
        bfrag8 af = wp[((size_t)((k * 8 + mtg0 + m) * 4 + kk)) * 64 + lane];
        acc[m][0] = __builtin_amdgcn_mfma_f32_16x16x32_bf16(af, B0, acc[m][0], 0, 0, 0);
        acc[m][1] = __builtin_amdgcn_mfma_f32_16x16x32_bf16(af, B1, acc[m][1], 0, 0, 0);
      }
    }
  }

  // epilogue: bias + bf16 store + GN partials (fp32).
  float lsum = 0.f, lsq = 0.f;
  #pragma unroll
  for (int m = 0; m < 2; ++m) {
    int oc = (mtg0 + m) * 16 + g * 4;
    float4 bias = *(const float4*)(de_b + oc);
    #pragma unroll
    for (int n = 0; n < 2; ++n) {
      int pix = pixbase + (pb0 + n) * 16 + lp;
      f32x4 a = acc[m][n];
      float4 v = make_float4(a[0] + bias.x, a[1] + bias.y, a[2] + bias.z, a[3] + bias.w);
      *(uint2*)(d + (size_t)pix * 128 + oc) = make_uint2(cvtpk(v.x, v.y), cvtpk(v.z, v.w));
      lsum += v.x + v.y + v.z + v.w;
      lsq  += v.x * v.x + v.y * v.y + v.z * v.z + v.w * v.w;
    }
  }
  __syncthreads();
  r1[tid] = lsum; r2[tid] = lsq;
  __syncthreads();
  for (int st = 256; st > 0; st >>= 1) {
    if (tid < st) { r1[tid] += r1[tid + st]; r2[tid] += r2[tid + st]; }
    __syncthreads();
  }
  if (tid == 0) {
    int b = pixbase / HW_;
    atomicAdd(&gst[b * 2],     r1[0]);
    atomicAdd(&gst[b * 2 + 1], r2[0]);
  }
}

// ---------------- final: GN (inline finalize) + sigmoid gate + shortcut ----
__global__ __launch_bounds__(256) void k_final(
    const short* __restrict__ d, const short* __restrict__ nsamp,
    const float* __restrict__ gst, const float* __restrict__ gn_w,
    const float* __restrict__ gn_b, float* __restrict__ out) {
  __shared__ float t[128 * 33];
  int tid = threadIdx.x;
  int pixbase = blockIdx.x * 32;
  int b = pixbase / HW_;
  int hw0 = pixbase % HW_;
  const float invN = 1.f / (float)BATCH_STRIDE;
  float gm = gst[2 * b] * invN;
  float gr = rsqrtf(gst[2 * b + 1] * invN - gm * gm + 1e-5f);

  int px0 = tid >> 3;
  int c0  = (tid & 7) * 16;
  const short* dp = d + ((size_t)(pixbase + px0)) * 128 + c0;
  const short* np = nsamp + ((size_t)(pixbase + px0)) * 128 + c0;
  bfrag8 dv0 = *(const bfrag8*)dp;
  bfrag8 dv1 = *(const bfrag8*)(dp + 8);
  bfrag8 sv0 = *(const bfrag8*)np;
  bfrag8 sv1 = *(const bfrag8*)(np + 8);
  #pragma unroll
  for (int q = 0; q < 4; ++q) {
    int c = c0 + q * 4;
    float4 w4 = *(const float4*)(gn_w + c);
    float4 b4 = *(const float4*)(gn_b + c);
    #pragma unroll
    for (int e = 0; e < 4; ++e) {
      int idx = q * 4 + e;
      float dvx = bf2f(idx < 8 ? dv0[idx & 7] : dv1[idx & 7]);
      float svn = bf2f(idx < 8 ? sv0[idx & 7] : sv1[idx & 7]);
      float wx  = e == 0 ? w4.x : (e == 1 ? w4.y : (e == 2 ? w4.z : w4.w));
      float bx  = e == 0 ? b4.x : (e == 1 ? b4.y : (e == 2 ? b4.z : b4.w));
      float dn = (dvx - gm) * gr * wx + bx;
      float gg = 1.f / (1.f + expf(-dn));
      t[(c + e) * 33 + px0] = svn * (1.f + gg);
    }
  }
  __syncthreads();
  if (tid < 128) {
    float* op = out + (size_t)(b * 128 + tid) * HW_ + hw0;
    #pragma unroll
    for (int p4 = 0; p4 < 8; ++p4) {
      float4 v = make_float4(t[tid * 33 + p4 * 4], t[tid * 33 + p4 * 4 + 1],
                             t[tid * 33 + p4 * 4 + 2], t[tid * 33 + p4 * 4 + 3]);
      *(float4*)(op + p4 * 4) = v;
    }
  }
}

extern "C" void kernel_launch(void* const* d_in, const int* in_sizes, int n_in,
                              void* d_out, int out_size, void* d_ws, size_t ws_size,
                              hipStream_t stream) {
  (void)in_sizes; (void)n_in; (void)out_size; (void)ws_size;
  const float* x     = (const float*)d_in[0];
  const float* dw_w  = (const float*)d_in[1];
  const float* dw_b  = (const float*)d_in[2];
  const float* pw_w  = (const float*)d_in[3];
  const float* pw_b  = (const float*)d_in[4];
  const float* off_w = (const float*)d_in[5];
  const float* off_b = (const float*)d_in[6];
  const float* de_w  = (const float*)d_in[7];
  const float* de_b  = (const float*)d_in[8];
  const float* gn_w  = (const float*)d_in[9];
  const float* gn_b  = (const float*)d_in[10];
  float* out = (float*)d_out;

  float* ws   = (float*)d_ws;
  float* off  = ws;                        // [18][NPIX] offsets (oc-major)
  short* wtb  = (short*)(off + NPIX * 18); // bf16 A-frag de_w (147456 shorts)
  short* wob  = wtb + 147456;              // bf16 A-frag off_w (36864 shorts)
  short* pwb  = wob + 36864;               // bf16 A-frag pw_w (16384 shorts)
  float* ist  = (float*)(pwb + 16384);     // [B][C][2] sum,sumsq
  float* gst  = ist + 1024;                // [B][2]
  short* sbf  = (short*)(gst + 8);         // bf16 dw+pw out, pixel-major (NPIX*128)
  short* dbf  = sbf + (size_t)NPIX * 128;  // bf16 deform out, pixel-major
  short* nsamp = dbf + (size_t)NPIX * 128; // bf16 normalized, pixel-major

  k_transpose_w<<<576, 256, 0, stream>>>(de_w, off_w, pw_w, wtb, wob, pwb, ist);
  k_pw<<<NPIX / 32, 256, 0, stream>>>(x, dw_w, dw_b, pwb, pw_b, sbf, ist);
  k_norm<<<NPIX * 16 / 256, 256, 0, stream>>>(sbf, ist, nsamp);
  k_offgemm<<<NPIX / 128, 256, 0, stream>>>(nsamp, wob, off_b, off);
  k_deform_f<<<NPIX / 64, 512, 0, stream>>>(nsamp, off, wtb, de_b, dbf, gst);
  k_final<<<NPIX / 32, 256, 0, stream>>>(dbf, nsamp, gst, gn_w, gn_b, out);
}

// Round 23
// 135.743 us; speedup vs baseline: 1.0692x; 1.0692x over previous
//
#include <hip/hip_runtime.h>
#include <hip/hip_bf16.h>
#include <math.h>

#define B_    4
#define C_    128
#define H_    96
#define W_    96
#define HW_   9216          // H*W
#define NPIX  36864         // B*HW
#define BHWC  4718592       // B*HW*C
#define BATCH_STRIDE 1179648 // HW*C

typedef __attribute__((ext_vector_type(8))) short bfrag8;
typedef __attribute__((ext_vector_type(4))) float f32x4;

static __device__ __forceinline__ short f2bf(float f) {
  __hip_bfloat16 h = __float2bfloat16(f);
  short s;
  __builtin_memcpy(&s, &h, 2);
  return s;
}
static __device__ __forceinline__ float bf2f(short s) {
  unsigned u = ((unsigned)(unsigned short)s) << 16;
  float f;
  __builtin_memcpy(&f, &u, 4);
  return f;
}
// pack two f32 -> two bf16 (RNE) in one instruction
static __device__ __forceinline__ unsigned cvtpk(float lo, float hi) {
  unsigned r;
  asm("v_cvt_pk_bf16_f32 %0, %1, %2" : "=v"(r) : "v"(lo), "v"(hi));
  return r;
}

// ---------------- weight transposes (+ zero stats accumulators) ------------
__global__ void k_transpose_w(const float* __restrict__ de_w,
                              const float* __restrict__ off_w,
                              const float* __restrict__ pw_w,
                              short* __restrict__ wtb, short* __restrict__ wob,
                              short* __restrict__ pwb, float* __restrict__ ist) {
  int i = blockIdx.x * 256 + threadIdx.x;
  if (i < 147456) {
    int j  = i & 7;
    int l  = (i >> 3) & 63;
    int kk = (i >> 9) & 3;
    int mt = (i >> 11) & 7;
    int k  = i >> 14;
    int oc = mt * 16 + (l & 15);
    int c  = kk * 32 + ((l >> 4) << 3) + j;
    wtb[i] = f2bf(de_w[(oc * 128 + c) * 9 + k]);
  }
  if (i < 36864) {
    int j  = i & 7;
    int l  = (i >> 3) & 63;
    int kk = (i >> 9) & 3;
    int mt = (i >> 11) & 1;
    int k  = i >> 12;
    int oc = mt * 16 + (l & 15);
    int c  = kk * 32 + ((l >> 4) << 3) + j;
    wob[i] = (oc < 18) ? f2bf(off_w[(oc * 128 + c) * 9 + k]) : (short)0;
  }
  if (i < 16384) {
    int j  = i & 7;
    int l  = (i >> 3) & 63;
    int kk = (i >> 9) & 3;
    int mt = i >> 11;
    int oc = mt * 16 + (l & 15);
    int c  = kk * 32 + ((l >> 4) << 3) + j;
    pwb[i] = f2bf(pw_w[oc * 128 + c]);
  }
  if (i < 1032) ist[i] = 0.f;   // zero ist[1024] + gst[8]
}

// ------ fused depthwise+pointwise MFMA + IN-stats : x -> sbf(bf16), ist ------
// block = 64 pix x 128 oc, 4 waves; grid NPIX/64 = 576 (R21 proven).
__global__ __launch_bounds__(256) void k_pw(
    const float* __restrict__ x, const float* __restrict__ dw_w,
    const float* __restrict__ dw_b, const short* __restrict__ pwb,
    const float* __restrict__ pw_b, short* __restrict__ sbf,
    float* __restrict__ ist) {
  __shared__ short lb[4][4][64][8];   // [pb][kk][lane][j], 16 KB
  __shared__ float ps[4][128], pq2[4][128];  // 4 KB stats partials
  int tid = threadIdx.x;
  int pixbase = blockIdx.x * 64;
  int b = pixbase / HW_;
  int hw0 = pixbase % HW_;

  int pixloc = tid & 63, cq = tid >> 6;
  {
    int hw = hw0 + pixloc;
    int y = hw / 96, xx = hw % 96;
    const float* xb = x + (size_t)b * 128 * HW_;
    int toff[9];
    float tmask[9];
    #pragma unroll
    for (int dy = 0; dy < 3; ++dy) {
      #pragma unroll
      for (int dx = 0; dx < 3; ++dx) {
        int sy = y + dy - 1, sx = xx + dx - 1;
        bool vld = ((unsigned)sy < 96u) && ((unsigned)sx < 96u);
        int syc = min(max(sy, 0), 95), sxc = min(max(sx, 0), 95);
        toff[dy * 3 + dx] = syc * 96 + sxc;
        tmask[dy * 3 + dx] = vld ? 1.f : 0.f;
      }
    }
    #pragma unroll
    for (int it = 0; it < 4; ++it) {
      int c8 = cq * 4 + it;
      int c0 = c8 * 8;
      float v[8];
      #pragma unroll
      for (int j = 0; j < 8; ++j) {
        int c = c0 + j;
        const float* xp = xb + (size_t)c * HW_;
        const float* wp = dw_w + c * 9;
        float a = dw_b[c];
        #pragma unroll
        for (int t9 = 0; t9 < 9; ++t9)
          a = fmaf(xp[toff[t9]] * tmask[t9], wp[t9], a);
        v[j] = a;
      }
      unsigned o0 = cvtpk(v[0], v[1]), o1 = cvtpk(v[2], v[3]);
      unsigned o2 = cvtpk(v[4], v[5]), o3 = cvtpk(v[6], v[7]);
      *(uint4*)&lb[pixloc >> 4][c8 >> 2][(c8 & 3) * 16 + (pixloc & 15)][0] =
          make_uint4(o0, o1, o2, o3);
    }
  }
  __syncthreads();

  int lane = tid & 63, wv = tid >> 6;
  int lp = lane & 15, g = lane >> 4;
  const bfrag8* wp8 = (const bfrag8*)pwb;

  f32x4 acc[8];
  #pragma unroll
  for (int m = 0; m < 8; ++m) acc[m] = (f32x4){0.f, 0.f, 0.f, 0.f};

  #pragma unroll
  for (int kk = 0; kk < 4; ++kk) {
    bfrag8 Bf = *(const bfrag8*)&lb[wv][kk][lane][0];
    #pragma unroll
    for (int m = 0; m < 8; ++m) {
      bfrag8 af = wp8[((size_t)(m * 4 + kk)) * 64 + lane];
      acc[m] = __builtin_amdgcn_mfma_f32_16x16x32_bf16(af, Bf, acc[m], 0, 0, 0);
    }
  }

  int pix = pixbase + wv * 16 + lp;
  #pragma unroll
  for (int m = 0; m < 8; ++m) {
    int oc = m * 16 + g * 4;
    float4 bias = *(const float4*)(pw_b + oc);
    f32x4 a = acc[m];
    float4 v = make_float4(a[0] + bias.x, a[1] + bias.y, a[2] + bias.z, a[3] + bias.w);
    *(uint2*)(sbf + (size_t)pix * 128 + oc) = make_uint2(cvtpk(v.x, v.y), cvtpk(v.z, v.w));
    float t0 = v.x, t1 = v.y, t2 = v.z, t3 = v.w;
    float u0 = v.x * v.x, u1 = v.y * v.y, u2 = v.z * v.z, u3 = v.w * v.w;
    #pragma unroll
    for (int mask = 1; mask <= 8; mask <<= 1) {
      t0 += __shfl_xor(t0, mask); t1 += __shfl_xor(t1, mask);
      t2 += __shfl_xor(t2, mask); t3 += __shfl_xor(t3, mask);
      u0 += __shfl_xor(u0, mask); u1 += __shfl_xor(u1, mask);
      u2 += __shfl_xor(u2, mask); u3 += __shfl_xor(u3, mask);
    }
    if (lp == 0) {
      ps[wv][oc + 0] = t0; ps[wv][oc + 1] = t1; ps[wv][oc + 2] = t2; ps[wv][oc + 3] = t3;
      pq2[wv][oc + 0] = u0; pq2[wv][oc + 1] = u1; pq2[wv][oc + 2] = u2; pq2[wv][oc + 3] = u3;
    }
  }
  __syncthreads();
  if (tid < 128) {
    float su = ps[0][tid] + ps[1][tid] + ps[2][tid] + ps[3][tid];
    float sq = pq2[0][tid] + pq2[1][tid] + pq2[2][tid] + pq2[3][tid];
    atomicAdd(&ist[(size_t)(b * 128 + tid) * 2],     su);
    atomicAdd(&ist[(size_t)(b * 128 + tid) * 2 + 1], sq);
  }
}

// ---------------- normalize sbf(bf16) -> bf16 pixel-major nsamp ------------
__global__ __launch_bounds__(256) void k_norm(
    const short* __restrict__ sbf, const float* __restrict__ ist,
    short* __restrict__ nsamp) {
  int t = blockIdx.x * 256 + threadIdx.x;   // t < NPIX*16
  int pix = t >> 4; int c0 = (t & 15) * 8;
  int b = pix / HW_;
  bfrag8 sv = *(const bfrag8*)(sbf + (size_t)pix * 128 + c0);
  bfrag8 o;
  #pragma unroll
  for (int j = 0; j < 8; ++j) {
    size_t ci = (size_t)(b * 128 + c0 + j) * 2;
    float mean = ist[ci] * (1.f / 9216.f);
    float var  = ist[ci + 1] * (1.f / 9216.f) - mean * mean;
    float rs = rsqrtf(var + 1e-5f);
    o[j] = f2bf(fmaxf((bf2f(sv[j]) - mean) * rs, 0.f));
  }
  *(bfrag8*)(nsamp + (size_t)pix * 128 + c0) = o;
}

// ---------------- offset conv as MFMA GEMM with shifted fragments ----------
__global__ __launch_bounds__(256) void k_offgemm(
    const short* __restrict__ nsamp, const short* __restrict__ wob,
    const float* __restrict__ off_b, float* __restrict__ off) {
  int tid = threadIdx.x;
  int lane = tid & 63, wv = tid >> 6;
  int p0 = blockIdx.x * 128 + wv * 32;
  int lp = lane & 15, g = lane >> 4;
  const bfrag8* np = (const bfrag8*)nsamp;
  const bfrag8* wp = (const bfrag8*)wob;

  f32x4 acc[2][2];
  #pragma unroll
  for (int m = 0; m < 2; ++m)
    #pragma unroll
    for (int n = 0; n < 2; ++n) acc[m][n] = (f32x4){0.f, 0.f, 0.f, 0.f};

  int pn0 = p0 + lp, pn1 = p0 + 16 + lp;
  int x0_ = pn0 % 96, y0_ = (pn0 % HW_) / 96;
  int x1_ = pn1 % 96, y1_ = (pn1 % HW_) / 96;
  const bfrag8 zf = {0, 0, 0, 0, 0, 0, 0, 0};

  for (int k = 0; k < 9; ++k) {
    int dy = k / 3 - 1, dx = k % 3 - 1;
    int sh = dy * 96 + dx;
    bool v0 = ((unsigned)(x0_ + dx) < 96u) && ((unsigned)(y0_ + dy) < 96u);
    bool v1 = ((unsigned)(x1_ + dx) < 96u) && ((unsigned)(y1_ + dy) < 96u);
    int q0 = min(max(pn0 + sh, 0), NPIX - 1);
    int q1 = min(max(pn1 + sh, 0), NPIX - 1);
    size_t a0 = (size_t)q0 * 16 + g;
    size_t a1 = (size_t)q1 * 16 + g;
    #pragma unroll
    for (int kk = 0; kk < 4; ++kk) {
      bfrag8 B0 = np[a0 + kk * 4]; B0 = v0 ? B0 : zf;
      bfrag8 B1 = np[a1 + kk * 4]; B1 = v1 ? B1 : zf;
      bfrag8 A0 = wp[((size_t)(k * 2 + 0) * 4 + kk) * 64 + lane];
      bfrag8 A1 = wp[((size_t)(k * 2 + 1) * 4 + kk) * 64 + lane];
      acc[0][0] = __builtin_amdgcn_mfma_f32_16x16x32_bf16(A0, B0, acc[0][0], 0, 0, 0);
      acc[0][1] = __builtin_amdgcn_mfma_f32_16x16x32_bf16(A0, B1, acc[0][1], 0, 0, 0);
      acc[1][0] = __builtin_amdgcn_mfma_f32_16x16x32_bf16(A1, B0, acc[1][0], 0, 0, 0);
      acc[1][1] = __builtin_amdgcn_mfma_f32_16x16x32_bf16(A1, B1, acc[1][1], 0, 0, 0);
    }
  }

  #pragma unroll
  for (int mt = 0; mt < 2; ++mt) {
    #pragma unroll
    for (int r = 0; r < 4; ++r) {
      int oc = mt * 16 + g * 4 + r;
      if (oc < 18) {
        float bb = off_b[oc];
        off[(size_t)oc * NPIX + p0 + lp]      = acc[mt][0][r] + bb;
        off[(size_t)oc * NPIX + p0 + 16 + lp] = acc[mt][1][r] + bb;
      }
    }
  }
}

// ---------------- fused deform: 64-pix blocks, 8 waves (R21 proven) --------
__global__ __launch_bounds__(512) void k_deform_f(
    const short* __restrict__ nsamp, const float* __restrict__ off,
    const short* __restrict__ wtb, const float* __restrict__ de_b,
    short* __restrict__ d, float* __restrict__ gst) {
  __shared__ short lbuf[2][4][16][17][8];  // 34.8 KB
  __shared__ float offl[18][64];           // 4.6 KB
  __shared__ float r1[512], r2[512];
  int tid = threadIdx.x;
  int bid = blockIdx.x;
  int wg = (bid & 7) * 72 + (bid >> 3);    // bijective for 576
  int pixbase = wg * 64;

  int lane = tid & 63, wv = tid >> 6;      // wv 0..7
  int lp = lane & 15, g = lane >> 4;
  int pq = lane >> 4, ch = lane & 15;      // sampling role

  // stage offsets for this block's 64 pixels: 18 x 64 = 1152 floats
  #pragma unroll
  for (int t = 0; t < 3; ++t) {
    int i = t * 512 + tid;
    if (i < 1152)
      offl[i >> 6][i & 63] = off[(size_t)(i >> 6) * NPIX + pixbase + (i & 63)];
  }
  __syncthreads();

  // per-q pixel constants (sampling role)
  int lpixA[2], ysA[2], xsA[2], qbA[2];
  #pragma unroll
  for (int q = 0; q < 2; ++q) {
    int lpix = wv * 8 + q * 4 + pq;
    int pix = pixbase + lpix;
    int hw = pix % HW_;
    lpixA[q] = lpix;
    ysA[q] = hw / 96;
    xsA[q] = hw % 96;
    qbA[q] = (pix / HW_) * HW_;
  }

  // mfma role
  int mtg0 = (wv & 3) * 2;
  int pb0  = (wv >> 2) * 2;
  const bfrag8* wp = (const bfrag8*)wtb;

  f32x4 acc[2][2];
  #pragma unroll
  for (int m = 0; m < 2; ++m)
    #pragma unroll
    for (int n = 0; n < 2; ++n) acc[m][n] = (f32x4){0.f, 0.f, 0.f, 0.f};

  bfrag8 cs0[2][4], cs1[2][4];   // two corner-register sets

  auto ISSUE = [&](int k, bfrag8 (&cs)[2][4]) {
    #pragma unroll
    for (int q = 0; q < 2; ++q) {
      float dy = offl[2 * k][lpixA[q]];
      float dx = offl[2 * k + 1][lpixA[q]];
      float py = (float)ysA[q] + (float)(k / 3 - 1) + dy;
      float px = (float)xsA[q] + (float)(k % 3 - 1) + dx;
      int y0 = (int)floorf(py), x0 = (int)floorf(px);
      int yc0 = min(max(y0, 0), 95), yc1 = min(max(y0 + 1, 0), 95);
      int xc0 = min(max(x0, 0), 95), xc1 = min(max(x0 + 1, 0), 95);
      const short* base = nsamp + (size_t)ch * 8;
      cs[q][0] = *(const bfrag8*)(base + (size_t)(qbA[q] + yc0 * 96 + xc0) * 128);
      cs[q][1] = *(const bfrag8*)(base + (size_t)(qbA[q] + yc0 * 96 + xc1) * 128);
      cs[q][2] = *(const bfrag8*)(base + (size_t)(qbA[q] + yc1 * 96 + xc0) * 128);
      cs[q][3] = *(const bfrag8*)(base + (size_t)(qbA[q] + yc1 * 96 + xc1) * 128);
    }
  };

  auto FINISH = [&](int k, bfrag8 (&cs)[2][4], int buf) {
    #pragma unroll
    for (int q = 0; q < 2; ++q) {
      float dy = offl[2 * k][lpixA[q]];
      float dx = offl[2 * k + 1][lpixA[q]];
      float py = (float)ysA[q] + (float)(k / 3 - 1) + dy;
      float px = (float)xsA[q] + (float)(k % 3 - 1) + dx;
      float y0f = floorf(py), x0f = floorf(px);
      float ly = py - y0f, lx = px - x0f;
      int y0 = (int)y0f, x0 = (int)x0f;
      bool vy0 = (y0 >= 0) && (y0 < 96), vy1 = (y0 + 1 >= 0) && (y0 + 1 < 96);
      bool vx0 = (x0 >= 0) && (x0 < 96), vx1 = (x0 + 1 >= 0) && (x0 + 1 < 96);
      float w00 = (vy0 && vx0) ? (1.f - ly) * (1.f - lx) : 0.f;
      float w01 = (vy0 && vx1) ? (1.f - ly) * lx : 0.f;
      float w10 = (vy1 && vx0) ? ly * (1.f - lx) : 0.f;
      float w11 = (vy1 && vx1) ? ly * lx : 0.f;
      float v[8];
      #pragma unroll
      for (int j = 0; j < 8; ++j) {
        v[j] = bf2f(cs[q][0][j]) * w00 + bf2f(cs[q][1][j]) * w01
             + bf2f(cs[q][2][j]) * w10 + bf2f(cs[q][3][j]) * w11;
      }
      unsigned o0 = cvtpk(v[0], v[1]), o1 = cvtpk(v[2], v[3]);
      unsigned o2 = cvtpk(v[4], v[5]), o3 = cvtpk(v[6], v[7]);
      int lpix = lpixA[q];
      *(uint4*)&lbuf[buf][lpix >> 4][lpix & 15][ch][0] = make_uint4(o0, o1, o2, o3);
    }
  };

  ISSUE(0, cs0);
  #pragma unroll
  for (int k = 0; k < 9; ++k) {
    if (k < 8) {
      if ((k + 1) & 1) ISSUE(k + 1, cs1);
      else             ISSUE(k + 1, cs0);
    }
    if (k & 1) FINISH(k, cs1, 1);
    else       FINISH(k, cs0, 0);
    __syncthreads();
    int cur = k & 1;
    #pragma unroll
    for (int kk = 0; kk < 4; ++kk) {
      bfrag8 B0 = *(const bfrag8*)&lbuf[cur][pb0 + 0][lp][kk * 4 + g][0];
      bfrag8 B1 = *(const bfrag8*)&lbuf[cur][pb0 + 1][lp][kk * 4 + g][0];
      #pragma unroll
      for (int m = 0; m < 2; ++m) {
        bfrag8 af = wp[((size_t)((k * 8 + mtg0 + m) * 4 + kk)) * 64 + lane];
        acc[m][0] = __builtin_amdgcn_mfma_f32_16x16x32_bf16(af, B0, acc[m][0], 0, 0, 0);
        acc[m][1] = __builtin_amdgcn_mfma_f32_16x16x32_bf16(af, B1, acc[m][1], 0, 0, 0);
      }
    }
  }

  // epilogue: bias + bf16 store + GN partials (fp32).
  float lsum = 0.f, lsq = 0.f;
  #pragma unroll
  for (int m = 0; m < 2; ++m) {
    int oc = (mtg0 + m) * 16 + g * 4;
    float4 bias = *(const float4*)(de_b + oc);
    #pragma unroll
    for (int n = 0; n < 2; ++n) {
      int pix = pixbase + (pb0 + n) * 16 + lp;
      f32x4 a = acc[m][n];
      float4 v = make_float4(a[0] + bias.x, a[1] + bias.y, a[2] + bias.z, a[3] + bias.w);
      *(uint2*)(d + (size_t)pix * 128 + oc) = make_uint2(cvtpk(v.x, v.y), cvtpk(v.z, v.w));
      lsum += v.x + v.y + v.z + v.w;
      lsq  += v.x * v.x + v.y * v.y + v.z * v.z + v.w * v.w;
    }
  }
  __syncthreads();
  r1[tid] = lsum; r2[tid] = lsq;
  __syncthreads();
  for (int st = 256; st > 0; st >>= 1) {
    if (tid < st) { r1[tid] += r1[tid + st]; r2[tid] += r2[tid + st]; }
    __syncthreads();
  }
  if (tid == 0) {
    int b = pixbase / HW_;
    atomicAdd(&gst[b * 2],     r1[0]);
    atomicAdd(&gst[b * 2 + 1], r2[0]);
  }
}

// ---------------- final: GN (inline finalize) + sigmoid gate + shortcut ----
__global__ __launch_bounds__(256) void k_final(
    const short* __restrict__ d, const short* __restrict__ nsamp,
    const float* __restrict__ gst, const float* __restrict__ gn_w,
    const float* __restrict__ gn_b, float* __restrict__ out) {
  __shared__ float t[128 * 33];
  int tid = threadIdx.x;
  int pixbase = blockIdx.x * 32;
  int b = pixbase / HW_;
  int hw0 = pixbase % HW_;
  const float invN = 1.f / (float)BATCH_STRIDE;
  float gm = gst[2 * b] * invN;
  float gr = rsqrtf(gst[2 * b + 1] * invN - gm * gm + 1e-5f);

  int px0 = tid >> 3;
  int c0  = (tid & 7) * 16;
  const short* dp = d + ((size_t)(pixbase + px0)) * 128 + c0;
  const short* np = nsamp + ((size_t)(pixbase + px0)) * 128 + c0;
  bfrag8 dv0 = *(const bfrag8*)dp;
  bfrag8 dv1 = *(const bfrag8*)(dp + 8);
  bfrag8 sv0 = *(const bfrag8*)np;
  bfrag8 sv1 = *(const bfrag8*)(np + 8);
  #pragma unroll
  for (int q = 0; q < 4; ++q) {
    int c = c0 + q * 4;
    float4 w4 = *(const float4*)(gn_w + c);
    float4 b4 = *(const float4*)(gn_b + c);
    #pragma unroll
    for (int e = 0; e < 4; ++e) {
      int idx = q * 4 + e;
      float dvx = bf2f(idx < 8 ? dv0[idx & 7] : dv1[idx & 7]);
      float svn = bf2f(idx < 8 ? sv0[idx & 7] : sv1[idx & 7]);
      float wx  = e == 0 ? w4.x : (e == 1 ? w4.y : (e == 2 ? w4.z : w4.w));
      float bx  = e == 0 ? b4.x : (e == 1 ? b4.y : (e == 2 ? b4.z : b4.w));
      float dn = (dvx - gm) * gr * wx + bx;
      float gg = 1.f / (1.f + expf(-dn));
      t[(c + e) * 33 + px0] = svn * (1.f + gg);
    }
  }
  __syncthreads();
  if (tid < 128) {
    float* op = out + (size_t)(b * 128 + tid) * HW_ + hw0;
    #pragma unroll
    for (int p4 = 0; p4 < 8; ++p4) {
      float4 v = make_float4(t[tid * 33 + p4 * 4], t[tid * 33 + p4 * 4 + 1],
                             t[tid * 33 + p4 * 4 + 2], t[tid * 33 + p4 * 4 + 3]);
      *(float4*)(op + p4 * 4) = v;
    }
  }
}

extern "C" void kernel_launch(void* const* d_in, const int* in_sizes, int n_in,
                              void* d_out, int out_size, void* d_ws, size_t ws_size,
                              hipStream_t stream) {
  (void)in_sizes; (void)n_in; (void)out_size; (void)ws_size;
  const float* x     = (const float*)d_in[0];
  const float* dw_w  = (const float*)d_in[1];
  const float* dw_b  = (const float*)d_in[2];
  const float* pw_w  = (const float*)d_in[3];
  const float* pw_b  = (const float*)d_in[4];
  const float* off_w = (const float*)d_in[5];
  const float* off_b = (const float*)d_in[6];
  const float* de_w  = (const float*)d_in[7];
  const float* de_b  = (const float*)d_in[8];
  const float* gn_w  = (const float*)d_in[9];
  const float* gn_b  = (const float*)d_in[10];
  float* out = (float*)d_out;

  float* ws   = (float*)d_ws;
  float* off  = ws;                        // [18][NPIX] offsets (oc-major)
  short* wtb  = (short*)(off + NPIX * 18); // bf16 A-frag de_w (147456 shorts)
  short* wob  = wtb + 147456;              // bf16 A-frag off_w (36864 shorts)
  short* pwb  = wob + 36864;               // bf16 A-frag pw_w (16384 shorts)
  float* ist  = (float*)(pwb + 16384);     // [B][C][2] sum,sumsq
  float* gst  = ist + 1024;                // [B][2]
  short* sbf  = (short*)(gst + 8);         // bf16 dw+pw out, pixel-major (NPIX*128)
  short* dbf  = sbf + (size_t)NPIX * 128;  // bf16 deform out, pixel-major
  short* nsamp = dbf + (size_t)NPIX * 128; // bf16 normalized, pixel-major

  k_transpose_w<<<576, 256, 0, stream>>>(de_w, off_w, pw_w, wtb, wob, pwb, ist);
  k_pw<<<NPIX / 64, 256, 0, stream>>>(x, dw_w, dw_b, pwb, pw_b, sbf, ist);
  k_norm<<<NPIX * 16 / 256, 256, 0, stream>>>(sbf, ist, nsamp);
  k_offgemm<<<NPIX / 128, 256, 0, stream>>>(nsamp, wob, off_b, off);
  k_deform_f<<<NPIX / 64, 512, 0, stream>>>(nsamp, off, wtb, de_b, dbf, gst);
  k_final<<<NPIX / 32, 256, 0, stream>>>(dbf, nsamp, gst, gn_w, gn_b, out);
}